// Round 5
// baseline (2949.803 us; speedup 1.0000x reference)
//
#include <hip/hip_runtime.h>
#include <hip/hip_bf16.h>

typedef __hip_bfloat16 bf16;
typedef __attribute__((ext_vector_type(8))) short short8;
typedef __attribute__((ext_vector_type(4))) float f32x4;

constexpr int BB  = 64;
constexpr int TT  = 351;
constexpr int DD  = 512;
constexpr int HH  = 8;
constexpr int DK  = 64;
constexpr int FF  = 1024;
constexpr int LL  = 3;
constexpr int MT  = BB * TT;      // 22464
constexpr int TD  = TT * DD;

constexpr int QT  = 16;                      // q rows per attn block
constexpr int NQT = (TT + QT - 1) / QT;      // 22
constexpr int VTS = 352;                     // V^T row stride (even, >=TT+1)

// converted-weight layout in d_out (elements, bf16)
constexpr size_t LW      = 3407872;          // per-layer stride
constexpr size_t OFF_QKV = 0;                // [1536][512]
constexpr size_t OFF_P   = 786432;           // [512][512]
constexpr size_t OFF_O   = 1048576;          // [512][512]
constexpr size_t OFF_W1  = 1310720;          // [1024][512]
constexpr size_t OFF_W2  = 1835008;          // [3][512][1024]

__device__ __forceinline__ float us2f(unsigned short u) {
    union { unsigned int i; float f; } c; c.i = ((unsigned int)u) << 16; return c.f;
}
__device__ __forceinline__ float bf2f(bf16 h) { return __bfloat162float(h); }
__device__ __forceinline__ bf16  f2bf(float f) { return __float2bfloat16(f); }
__device__ __forceinline__ float ldin(const void* p, size_t i, bool f32) {
    return f32 ? ((const float*)p)[i] : bf2f(((const bf16*)p)[i]);
}
__device__ __forceinline__ unsigned short f2us(float f) {
    bf16 h = f2bf(f); return *reinterpret_cast<unsigned short*>(&h);
}

// ---------------------------------------------------------------------------
// dtype detect: ln1_a is all-ones. fp32 1.0f low u16 = 0x0000; bf16 1.0=0x3F80
// ---------------------------------------------------------------------------
__global__ void detect_kernel(const unsigned short* ln1a, int* flag) {
    if (threadIdx.x == 0 && blockIdx.x == 0)
        *flag = (ln1a[0] == 0) ? 1 : 0;   // 1 = inputs are fp32
}

// ---------------------------------------------------------------------------
// weight conversion into wbuf (d_out scratch). mode 0: plain copy.
// mode 1: W2 transpose  dst[j][n][f] = src[n][f][j]
// ---------------------------------------------------------------------------
__global__ __launch_bounds__(256) void cvt_kernel(
    const void* __restrict__ src, size_t S, size_t slstride,
    bf16* __restrict__ dst, size_t doff, int nl, int mode,
    const int* __restrict__ dflag)
{
    const bool f32 = (*dflag != 0);
    size_t i = (size_t)blockIdx.x * 256 + threadIdx.x;
    size_t total = (size_t)nl * S;
    if (i >= total) return;
    size_t l = i / S, e = i - l * S;
    size_t se;
    if (mode == 1) {
        size_t j = e >> 19;
        size_t nf = e & ((1u << 19) - 1);
        size_t n = nf >> 10, f = nf & 1023;
        se = n * 3072 + f * 3 + j;
    } else se = e;
    dst[doff + l * LW + e] = f2bf(ldin(src, l * slstride + se, f32));
}

// ---------------------------------------------------------------------------
__global__ __launch_bounds__(256) void addpos_kernel(
    const void* __restrict__ xin, const void* __restrict__ pos, size_t posoff,
    float* __restrict__ xf, int init, const int* __restrict__ dflag)
{
    const bool f32 = (*dflag != 0);
    int i = blockIdx.x * 256 + threadIdx.x;
    if (i >= MT * DD) return;
    int td = i % TD;
    float p = ldin(pos, posoff + td, f32);
    if (init) xf[i] = ldin(xin, i, f32) + p;
    else      xf[i] += p;
}

// ---------------------------------------------------------------------------
// LayerNorm (torch: unbiased std (n-1), eps added to std)
// ---------------------------------------------------------------------------
__global__ __launch_bounds__(256) void ln_kernel(
    const float* __restrict__ xf, const void* __restrict__ ga, size_t gaoff,
    const void* __restrict__ gb, size_t gboff,
    void* __restrict__ out, int final_o, const int* __restrict__ dflag)
{
    const bool f32 = (*dflag != 0);
    __shared__ float red[256];
    const int row = blockIdx.x;
    const int tid = threadIdx.x;
    const float* xr = xf + (size_t)row * DD;
    float x0 = xr[tid], x1 = xr[tid + 256];

    red[tid] = x0 + x1;
    __syncthreads();
    for (int o = 128; o > 0; o >>= 1) {
        if (tid < o) red[tid] += red[tid + o];
        __syncthreads();
    }
    float mean = red[0] * (1.0f / 512.0f);
    __syncthreads();
    float c0 = x0 - mean, c1 = x1 - mean;
    red[tid] = c0 * c0 + c1 * c1;
    __syncthreads();
    for (int o = 128; o > 0; o >>= 1) {
        if (tid < o) red[tid] += red[tid + o];
        __syncthreads();
    }
    float stdv = sqrtf(red[0] * (1.0f / 511.0f));
    float inv = 1.0f / (stdv + 1e-6f);
    float v0 = ldin(ga, gaoff + tid,       f32) * c0 * inv + ldin(gb, gboff + tid,       f32);
    float v1 = ldin(ga, gaoff + tid + 256, f32) * c1 * inv + ldin(gb, gboff + tid + 256, f32);
    if (final_o && f32) {
        float* orow = (float*)out + (size_t)row * DD;
        orow[tid] = v0; orow[tid + 256] = v1;
    } else {
        bf16* orow = (bf16*)out + (size_t)row * DD;
        orow[tid] = f2bf(v0); orow[tid + 256] = f2bf(v1);
    }
}

// ---------------------------------------------------------------------------
// MFMA GEMM: C[M,N] = A[M,K] @ W[N,K]^T (+bias). 128x128 tile, 4 waves.
// mode 0: scatter bf16 (b,h,t,dk); which=n>>9: 0/1 -> outp slots, 2 -> vt
//         (V transposed [b,h][dk][t], stride VTS, elem TT zeroed)
// mode 1: relu -> bf16 [M][N]
// mode 2: fp32 += into xf [M][DD]
// ---------------------------------------------------------------------------
__global__ __launch_bounds__(256) void mgemm_kernel(
    const void* __restrict__ A, size_t aoff, int a_ext,
    const bf16* __restrict__ W,
    const void* __restrict__ b0, const void* __restrict__ b1p,
    const void* __restrict__ b2p, size_t boff,
    void* __restrict__ outp, bf16* __restrict__ vt,
    int M, int N, int K, int mode, int chN,
    const int* __restrict__ dflag)
{
    const bool f32 = (*dflag != 0);
    const bool a32 = a_ext && f32;
    __shared__ unsigned short As[128][40];
    __shared__ unsigned short Bs[128][40];
    const int tid = threadIdx.x;
    const int n0 = blockIdx.x * 128, m0 = blockIdx.y * 128;

    const int lane = tid & 63, wv = tid >> 6;
    const int wm = wv >> 1, wn = wv & 1;
    const int q = lane >> 4, lm = lane & 15;

    f32x4 acc[4][4] = {};

    for (int k0 = 0; k0 < K; k0 += 32) {
        #pragma unroll
        for (int part = 0; part < 2; ++part) {
            int idx = part * 256 + tid;
            int row = idx >> 2;
            int seg = (idx & 3) * 8;
            int grow = m0 + row; if (grow >= M) grow = M - 1;
            if (a32) {
                const float* ap = (const float*)A + aoff + (size_t)grow * K + k0 + seg;
                union { unsigned short us[8]; int4 v; } t;
                #pragma unroll
                for (int e = 0; e < 8; ++e) t.us[e] = f2us(ap[e]);
                *(int4*)&As[row][seg] = t.v;
            } else {
                *(int4*)&As[row][seg] =
                    *(const int4*)((const bf16*)A + aoff + (size_t)grow * K + k0 + seg);
            }
            *(int4*)&Bs[row][seg] =
                *(const int4*)(W + (size_t)(n0 + row) * K + k0 + seg);
        }
        __syncthreads();
        short8 af[4], bfv[4];
        #pragma unroll
        for (int i = 0; i < 4; ++i) af[i]  = *(const short8*)&As[wm * 64 + i * 16 + lm][q * 8];
        #pragma unroll
        for (int j = 0; j < 4; ++j) bfv[j] = *(const short8*)&Bs[wn * 64 + j * 16 + lm][q * 8];
        #pragma unroll
        for (int i = 0; i < 4; ++i)
            #pragma unroll
            for (int j = 0; j < 4; ++j)
                acc[i][j] = __builtin_amdgcn_mfma_f32_16x16x32_bf16(af[i], bfv[j], acc[i][j], 0, 0, 0);
        __syncthreads();
    }

    #pragma unroll
    for (int i = 0; i < 4; ++i) {
        #pragma unroll
        for (int j = 0; j < 4; ++j) {
            #pragma unroll
            for (int r = 0; r < 4; ++r) {
                int m = m0 + wm * 64 + i * 16 + q * 4 + r;
                if (m >= M) continue;
                int n = n0 + wn * 64 + j * 16 + lm;
                float c = acc[i][j][r];
                if (mode == 0) {
                    int which = n >> 9;
                    int nn = n & 511;
                    const void* bp = which == 0 ? b0 : (which == 1 ? b1p : b2p);
                    if (bp) c += ldin(bp, boff + nn, f32);
                    int b = m / TT, t = m - b * TT;
                    int h = nn >> 6, dk = nn & 63;
                    if (which == 2) {
                        size_t idxv = ((size_t)(b * HH + h) * DK + dk) * VTS + t;
                        vt[idxv] = f2bf(c);
                        if (t == TT - 1) vt[idxv + 1] = f2bf(0.0f);  // keep pad NaN-free
                    } else {
                        ((bf16*)outp)[(size_t)which * chN +
                                      ((((size_t)b * HH + h) * TT + t) * DK) + dk] = f2bf(c);
                    }
                } else if (mode == 1) {
                    if (b0) c += ldin(b0, boff + n, f32);
                    ((bf16*)outp)[(size_t)m * N + n] = f2bf(fmaxf(c, 0.0f));
                } else {
                    if (b0) c += ldin(b0, boff + n, f32);
                    ((float*)outp)[(size_t)m * DD + n] += c;
                }
            }
        }
    }
}

// ---------------------------------------------------------------------------
// MFMA conv1d k=3 pad=1: y[m,n] = sum_j sum_f w2r[j][n][f] * h[m+j-1,f]
// += into xf (fp32) with bias. Hb chunk-local (batch-aligned).
// ---------------------------------------------------------------------------
__global__ __launch_bounds__(256) void mconv_kernel(
    const bf16* __restrict__ Hb, const bf16* __restrict__ Wc,
    const void* __restrict__ bias, size_t boff,
    float* __restrict__ xf, int M, const int* __restrict__ dflag)
{
    const bool f32 = (*dflag != 0);
    __shared__ unsigned short As[128][40];
    __shared__ unsigned short Bs[128][40];
    const int tid = threadIdx.x;
    const int n0 = blockIdx.x * 128, m0 = blockIdx.y * 128;

    const int lane = tid & 63, wv = tid >> 6;
    const int wm = wv >> 1, wn = wv & 1;
    const int q = lane >> 4, lm = lane & 15;

    // per-part staging geometry (constant across k)
    int rowP[2], segP[2], mloadP[2], trowP[2];
    bool inrP[2];
    #pragma unroll
    for (int part = 0; part < 2; ++part) {
        int idx = part * 256 + tid;
        rowP[part] = idx >> 2;
        segP[part] = (idx & 3) * 8;
        int mrow = m0 + rowP[part];
        inrP[part] = mrow < M;
        int mload = inrP[part] ? mrow : (M - 1);
        mloadP[part] = mload;
        trowP[part] = mload % TT;
    }

    f32x4 acc[4][4] = {};

    for (int j = 0; j < 3; ++j) {
        for (int k0 = 0; k0 < FF; k0 += 32) {
            #pragma unroll
            for (int part = 0; part < 2; ++part) {
                int row = rowP[part], seg = segP[part];
                int ts = trowP[part] + j - 1;
                bool valid = inrP[part] && ts >= 0 && ts < TT;
                if (valid) {
                    *(int4*)&As[row][seg] =
                        *(const int4*)(Hb + (size_t)(mloadP[part] + j - 1) * FF + k0 + seg);
                } else {
                    int4 z = {0, 0, 0, 0};
                    *(int4*)&As[row][seg] = z;
                }
                *(int4*)&Bs[row][seg] =
                    *(const int4*)(Wc + (size_t)j * 524288 + (size_t)(n0 + row) * FF + k0 + seg);
            }
            __syncthreads();
            short8 af[4], bfv[4];
            #pragma unroll
            for (int i = 0; i < 4; ++i) af[i]  = *(const short8*)&As[wm * 64 + i * 16 + lm][q * 8];
            #pragma unroll
            for (int jj = 0; jj < 4; ++jj) bfv[jj] = *(const short8*)&Bs[wn * 64 + jj * 16 + lm][q * 8];
            #pragma unroll
            for (int i = 0; i < 4; ++i)
                #pragma unroll
                for (int jj = 0; jj < 4; ++jj)
                    acc[i][jj] = __builtin_amdgcn_mfma_f32_16x16x32_bf16(af[i], bfv[jj], acc[i][jj], 0, 0, 0);
            __syncthreads();
        }
    }

    #pragma unroll
    for (int i = 0; i < 4; ++i) {
        #pragma unroll
        for (int jj = 0; jj < 4; ++jj) {
            #pragma unroll
            for (int r = 0; r < 4; ++r) {
                int m = m0 + wm * 64 + i * 16 + q * 4 + r;
                if (m >= M) continue;
                int n = n0 + wn * 64 + jj * 16 + lm;
                xf[(size_t)m * DD + n] += acc[i][jj][r] + ldin(bias, boff + n, f32);
            }
        }
    }
}

// ---------------------------------------------------------------------------
// Fused relative attention — round 5: QT=16, 38.9KB LDS -> 4 blocks/CU,
// V read transposed from global (written by QKV GEMM), no phase-5/Vt.
// ---------------------------------------------------------------------------
__global__ __launch_bounds__(256, 4) void attn_kernel(
    const bf16* __restrict__ Q, const bf16* __restrict__ Kb,
    const bf16* __restrict__ Vt, const bf16* __restrict__ P,
    const void* __restrict__ ubias, const void* __restrict__ vbias, size_t uvoff,
    bf16* __restrict__ ctx, const int* __restrict__ dflag)
{
    const bool f32 = (*dflag != 0);
    // ---- dispatch swizzle: tiles of one (b,h) land on one XCD ----
    const int d  = blockIdx.x + NQT * (blockIdx.y + HH * blockIdx.z);
    const int rr = d % (8 * NQT);
    const int g  = (d / (8 * NQT)) * 8 + (rr & 7);
    const int t  = rr >> 3;                 // 0..21
    const int b  = g >> 3;                  // chunk-local batch
    const int h  = g & 7;                   // head
    const int q0 = t * QT;

    const int tid  = threadIdx.x;
    const int lane = tid & 63;
    const int wv   = tid >> 6;      // wave 0..3
    const int lm   = lane & 15;
    const int q8   = lane >> 4;

    __shared__ __align__(16) float S[QT][354];               // 22656 B
    __shared__ __align__(16) unsigned short Abf[QT][356];    // 11392 B
    __shared__ __align__(16) unsigned short qu[QT][72];      //  2304 B
    __shared__ __align__(16) unsigned short qv[QT + 2][72];  //  2592 B

    const size_t base = (((size_t)b * HH + h) * TT) * DK;
    const float scale = 0.04419417382415922f;   // 1/sqrt(512)

    // ---- phase 1: Q staging (rows q0..q0+16) ----
    for (int i = tid; i < (QT + 1) * 64; i += 256) {
        int q = i >> 6, dd = i & 63;
        int qrow = q0 + q;
        float qq = (qrow < TT) ? bf2f(Q[base + (size_t)qrow * DK + dd]) : 0.0f;
        float vb = ldin(vbias, uvoff + h * DK + dd, f32);
        qv[q][dd] = f2us((qq + vb) * scale);
        if (q < QT) {
            float ub = ldin(ubias, uvoff + h * DK + dd, f32);
            qu[q][dd] = f2us((qq + ub) * scale);
        }
    }
    __syncthreads();

    // ---- preload K and P rows for all 6 iterations ----
    short8 kv0[6], kv1[6], pv0[6], pv1[6];
    #pragma unroll
    for (int it = 0; it < 6; ++it) {
        int jt = wv + it * 4;
        int kr = jt * 16 + lm; if (kr > TT - 1) kr = TT - 1;
        const short8* kp = (const short8*)(Kb + base + (size_t)kr * DK + q8 * 8);
        const short8* pp = (const short8*)(P  + base + (size_t)kr * DK + q8 * 8);
        kv0[it] = kp[0]; kv1[it] = kp[4];
        pv0[it] = pp[0]; pv1[it] = pp[4];
    }

    // ---- phase 2: content scores -> S ----
    {
        short8 afa = *(const short8*)&qu[lm][q8 * 8];
        short8 afb = *(const short8*)&qu[lm][32 + q8 * 8];
        #pragma unroll
        for (int it = 0; it < 6; ++it) {
            int jt = wv + it * 4;
            if (jt >= NQT) break;           // wave-uniform
            f32x4 a0 = {};
            a0 = __builtin_amdgcn_mfma_f32_16x16x32_bf16(afa, kv0[it], a0, 0, 0, 0);
            a0 = __builtin_amdgcn_mfma_f32_16x16x32_bf16(afb, kv1[it], a0, 0, 0, 0);
            int col = jt * 16 + lm;         // <= 351 < 354
            #pragma unroll
            for (int r = 0; r < 4; ++r)
                S[q8 * 4 + r][col] = a0[r];
        }
    }
    __syncthreads();

    // ---- phase 3: pos scores + branchless rel-shift scatter-add ----
    {
        short8 af0a = *(const short8*)&qv[lm][q8 * 8];
        short8 af0b = *(const short8*)&qv[lm][32 + q8 * 8];
        short8 af1a = {}, af1b = {};
        if (lm == 0) {                      // second tile: only row q0+16 real
            af1a = *(const short8*)&qv[QT][q8 * 8];
            af1b = *(const short8*)&qv[QT][32 + q8 * 8];
        }
        #pragma unroll
        for (int it = 0; it < 6; ++it) {
            int jt = wv + it * 4;
            if (jt >= NQT) break;           // wave-uniform
            f32x4 ac0 = {}, ac1 = {};
            ac0 = __builtin_amdgcn_mfma_f32_16x16x32_bf16(af0a, pv0[it], ac0, 0, 0, 0);
            ac0 = __builtin_amdgcn_mfma_f32_16x16x32_bf16(af0b, pv1[it], ac0, 0, 0, 0);
            ac1 = __builtin_amdgcn_mfma_f32_16x16x32_bf16(af1a, pv0[it], ac1, 0, 0, 0);
            ac1 = __builtin_amdgcn_mfma_f32_16x16x32_bf16(af1b, pv1[it], ac1, 0, 0, 0);
            int j = jt * 16 + lm;
            if (j < TT) {
                #pragma unroll
                for (int i = 0; i < 2; ++i) {
                    #pragma unroll
                    for (int r = 0; r < 4; ++r) {
                        int rl = i * 16 + q8 * 4 + r;     // local PSraw row
                        int rg = q0 + rl;                 // global row
                        float v = (i == 0) ? ac0[r] : ac1[r];
                        // cb=0 -> (rl, j+rg-350); cb=1 -> (rl-1, j+rg+1)
                        int cb  = (j + rg < TT - 1) ? 1 : 0;
                        int row = rl - cb;
                        int col = j + rg - (TT - 1) + cb * TT;
                        if (row >= 0 && row < QT) S[row][col] += v;
                    }
                }
            }
        }
    }
    __syncthreads();

    // ---- issue V^T fragment loads early (L2; latency hides under softmax) ----
    const bf16* vrp = Vt + ((size_t)(b * HH + h) * DK + wv * 16 + lm) * VTS;
    short8 bvv[11];
    #pragma unroll
    for (int ks = 0; ks < 11; ++ks)
        bvv[ks] = *(const short8*)(vrp + ks * 32 + q8 * 8);

    // ---- phase 4: register-file softmax (16 lanes/row) ----
    {
        const int row = tid >> 4, k0 = tid & 15;
        const float* Sr = S[row];
        float sv[22];
        #pragma unroll
        for (int i = 0; i < 22; ++i) {
            int k = k0 + 16 * i;
            sv[i] = (k < TT) ? Sr[k] : -1e30f;
        }
        float m = -1e30f;
        #pragma unroll
        for (int i = 0; i < 22; ++i) m = fmaxf(m, sv[i]);
        #pragma unroll
        for (int msk = 1; msk < 16; msk <<= 1) m = fmaxf(m, __shfl_xor(m, msk));
        float sum = 0.0f;
        #pragma unroll
        for (int i = 0; i < 22; ++i) {
            float e = __expf(sv[i] - m);
            sv[i] = e;
            sum += e;
        }
        #pragma unroll
        for (int msk = 1; msk < 16; msk <<= 1) sum += __shfl_xor(sum, msk);
        float rinv = 1.0f / sum;
        #pragma unroll
        for (int i = 0; i < 23; ++i) {
            int k = k0 + 16 * i;
            if (k < 356)
                Abf[row][k] = (k < TT && i < 22) ? f2us(sv[i] * rinv) : (unsigned short)0;
        }
    }
    __syncthreads();

    // ---- phase 6: PV -> ctx ----
    {
        f32x4 a0 = {};
        #pragma unroll
        for (int ks = 0; ks < 11; ++ks) {
            short8 av = *(const short8*)&Abf[lm][ks * 32 + q8 * 8];
            a0 = __builtin_amdgcn_mfma_f32_16x16x32_bf16(av, bvv[ks], a0, 0, 0, 0);
        }
        const int dd = wv * 16 + lm;
        #pragma unroll
        for (int r = 0; r < 4; ++r) {
            int qrow = q0 + q8 * 4 + r;
            if (qrow < TT)
                ctx[((size_t)b * TT + qrow) * DD + h * DK + dd] = f2bf(a0[r]);
        }
    }
}

// ---------------------------------------------------------------------------
extern "C" void kernel_launch(void* const* d_in, const int* in_sizes, int n_in,
                              void* d_out, int out_size, void* d_ws, size_t ws_size,
                              hipStream_t stream)
{
    (void)in_sizes; (void)n_in; (void)out_size;
    const void* x    = d_in[0];
    const void* mask = d_in[1];
    const void* pos  = d_in[2];
    const void* Wq   = d_in[3];
    const void* bq   = d_in[4];
    const void* Wk   = d_in[5];
    const void* bk   = d_in[6];
    const void* Wv   = d_in[7];
    const void* bv   = d_in[8];
    const void* Wp   = d_in[9];
    const void* ub   = d_in[10];
    const void* vbi  = d_in[11];
    const void* Wo   = d_in[12];
    const void* bo   = d_in[13];
    const void* l1a  = d_in[14];
    const void* l1b  = d_in[15];
    const void* l2a  = d_in[16];
    const void* l2b  = d_in[17];
    const void* W1   = d_in[18];
    const void* b1   = d_in[19];
    const void* W2   = d_in[20];
    const void* b2   = d_in[21];
    const void* fa   = d_in[22];
    const void* fb   = d_in[23];

    const size_t exf = (size_t)MT * DD;
    char* w = (char*)d_ws;
    int*   dflag = (int*)w;
    float* xf = (float*)(w + 256);
    bf16*  xn = (bf16*)(w + 256 + exf * 4);
    bf16*  sc = (bf16*)(w + 256 + exf * 6);
    bf16*  wbuf = (bf16*)d_out;   // weights (20.4MB) live in d_out until final LN

    // runtime chunk selection from ws_size
    // per-chunk-unit: Q,K,P buffers (3*TT*DD) + V^T (HH*DK*VTS), bf16
    const size_t fixed  = 256 + exf * 6;
    const size_t percha = (size_t)(3 * TT * DD + HH * DK * VTS) * 2;
    int cha = 8;
    if      (ws_size >= fixed + 64 * percha) cha = 64;
    else if (ws_size >= fixed + 32 * percha) cha = 32;
    else if (ws_size >= fixed + 16 * percha) cha = 16;
    const int nca = BB / cha;
    const int ma  = cha * TT;
    const int chf = (cha * 2 > 64) ? 64 : cha * 2;
    const int ncf = BB / chf;
    const int mf  = chf * TT;
    const int chN = cha * TT * DD;

    bf16* qc  = sc;                          // Q (slot0), K (slot1)
    bf16* pc  = sc + (size_t)2 * chN;        // P
    bf16* vtg = sc + (size_t)3 * chN;        // V^T [cha*HH*DK][VTS]
    bf16* hb  = sc;                          // FFN h (aliases, used later)

    dim3 blk(256);
    dim3 g_ep((MT * DD + 255) / 256);
    dim3 g_ln(MT);
    dim3 g_qkv(12, (ma + 127) / 128);
    dim3 g_p(4, (ma + 127) / 128);
    dim3 g_attn(NQT, HH, cha);
    dim3 g_o(4, (MT + 127) / 128);
    dim3 g_f1(8, (mf + 127) / 128);
    dim3 g_cv(4, (mf + 127) / 128);

    detect_kernel<<<dim3(1), dim3(64), 0, stream>>>((const unsigned short*)l1a, dflag);

    // convert weights (all layers) into d_out scratch
    auto cvt = [&](const void* src, size_t S, size_t doff, int mode) {
        dim3 g((unsigned)(((size_t)3 * S + 255) / 256));
        cvt_kernel<<<g, blk, 0, stream>>>(src, S, S, wbuf, doff, 3, mode, dflag);
    };
    cvt(Wq, 262144, OFF_QKV,          0);
    cvt(Wk, 262144, OFF_QKV + 262144, 0);
    cvt(Wv, 262144, OFF_QKV + 524288, 0);
    cvt(Wp, 262144, OFF_P,            0);
    cvt(Wo, 262144, OFF_O,            0);
    cvt(W1, 524288, OFF_W1,           0);
    cvt(W2, 1572864, OFF_W2,          1);

    for (int l = 0; l < LL; ++l) {
        const bf16* wl = wbuf + (size_t)l * LW;
        addpos_kernel<<<g_ep, blk, 0, stream>>>(x, pos, (size_t)l * TD, xf, l == 0, dflag);
        ln_kernel<<<g_ln, blk, 0, stream>>>(xf, l1a, (size_t)l * DD, l1b, (size_t)l * DD, xn, 0, dflag);
        for (int c = 0; c < nca; ++c) {
            bf16* xnc = xn + (size_t)c * ma * DD;
            mgemm_kernel<<<g_qkv, blk, 0, stream>>>(xnc, 0, 0, wl + OFF_QKV,
                bq, bk, bv, (size_t)l * DD, qc, vtg, ma, 1536, DD, 0, chN, dflag);
            mgemm_kernel<<<g_p, blk, 0, stream>>>(mask, (size_t)c * ma * DD, 1, wl + OFF_P,
                nullptr, nullptr, nullptr, 0, pc, nullptr, ma, DD, DD, 0, 0, dflag);
            attn_kernel<<<g_attn, blk, 0, stream>>>(qc, qc + chN, vtg, pc,
                ub, vbi, (size_t)l * HH * DK, xnc, dflag);
        }
        mgemm_kernel<<<g_o, blk, 0, stream>>>(xn, 0, 0, wl + OFF_O,
            bo, nullptr, nullptr, (size_t)l * DD, xf, nullptr, MT, DD, DD, 2, 0, dflag);
        ln_kernel<<<g_ln, blk, 0, stream>>>(xf, l2a, (size_t)l * DD, l2b, (size_t)l * DD, xn, 0, dflag);
        for (int c = 0; c < ncf; ++c) {
            mgemm_kernel<<<g_f1, blk, 0, stream>>>(xn + (size_t)c * mf * DD, 0, 0, wl + OFF_W1,
                b1, nullptr, nullptr, (size_t)l * FF, hb, nullptr, mf, FF, DD, 1, 0, dflag);
            mconv_kernel<<<g_cv, blk, 0, stream>>>(hb, wl + OFF_W2,
                b2, (size_t)l * DD, xf + (size_t)c * mf * DD, mf, dflag);
        }
    }
    ln_kernel<<<g_ln, blk, 0, stream>>>(xf, fa, 0, fb, 0, d_out, 1, dflag);
}

// Round 6
// 2312.046 us; speedup vs baseline: 1.2758x; 1.2758x over previous
//
#include <hip/hip_runtime.h>
#include <hip/hip_bf16.h>

typedef __hip_bfloat16 bf16;
typedef __attribute__((ext_vector_type(8))) short short8;
typedef __attribute__((ext_vector_type(4))) float f32x4;

constexpr int BB  = 64;
constexpr int TT  = 351;
constexpr int DD  = 512;
constexpr int HH  = 8;
constexpr int DK  = 64;
constexpr int FF  = 1024;
constexpr int LL  = 3;
constexpr int MT  = BB * TT;      // 22464
constexpr int TD  = TT * DD;

constexpr int QT  = 16;                      // q rows per attn block
constexpr int NQT = (TT + QT - 1) / QT;      // 22

// converted-weight layout in d_out (elements, bf16)
constexpr size_t LW      = 3407872;          // per-layer stride
constexpr size_t OFF_QKV = 0;                // [1536][512]
constexpr size_t OFF_P   = 786432;           // [512][512]
constexpr size_t OFF_O   = 1048576;          // [512][512]
constexpr size_t OFF_W1  = 1310720;          // [1024][512]
constexpr size_t OFF_W2  = 1835008;          // [3][512][1024]

__device__ __forceinline__ float us2f(unsigned short u) {
    union { unsigned int i; float f; } c; c.i = ((unsigned int)u) << 16; return c.f;
}
__device__ __forceinline__ float bf2f(bf16 h) { return __bfloat162float(h); }
__device__ __forceinline__ bf16  f2bf(float f) { return __float2bfloat16(f); }
__device__ __forceinline__ float ldin(const void* p, size_t i, bool f32) {
    return f32 ? ((const float*)p)[i] : bf2f(((const bf16*)p)[i]);
}
__device__ __forceinline__ unsigned short f2us(float f) {
    bf16 h = f2bf(f); return *reinterpret_cast<unsigned short*>(&h);
}

// ---------------------------------------------------------------------------
// dtype detect: ln1_a is all-ones. fp32 1.0f low u16 = 0x0000; bf16 1.0=0x3F80
// ---------------------------------------------------------------------------
__global__ void detect_kernel(const unsigned short* ln1a, int* flag) {
    if (threadIdx.x == 0 && blockIdx.x == 0)
        *flag = (ln1a[0] == 0) ? 1 : 0;   // 1 = inputs are fp32
}

// ---------------------------------------------------------------------------
// weight conversion into wbuf (d_out scratch). mode 0: plain copy.
// mode 1: W2 transpose  dst[j][n][f] = src[n][f][j]
// ---------------------------------------------------------------------------
__global__ __launch_bounds__(256) void cvt_kernel(
    const void* __restrict__ src, size_t S, size_t slstride,
    bf16* __restrict__ dst, size_t doff, int nl, int mode,
    const int* __restrict__ dflag)
{
    const bool f32 = (*dflag != 0);
    size_t i = (size_t)blockIdx.x * 256 + threadIdx.x;
    size_t total = (size_t)nl * S;
    if (i >= total) return;
    size_t l = i / S, e = i - l * S;
    size_t se;
    if (mode == 1) {
        size_t j = e >> 19;
        size_t nf = e & ((1u << 19) - 1);
        size_t n = nf >> 10, f = nf & 1023;
        se = n * 3072 + f * 3 + j;
    } else se = e;
    dst[doff + l * LW + e] = f2bf(ldin(src, l * slstride + se, f32));
}

// ---------------------------------------------------------------------------
__global__ __launch_bounds__(256) void addpos_kernel(
    const void* __restrict__ xin, const void* __restrict__ pos, size_t posoff,
    float* __restrict__ xf, int init, const int* __restrict__ dflag)
{
    const bool f32 = (*dflag != 0);
    int i = blockIdx.x * 256 + threadIdx.x;
    if (i >= MT * DD) return;
    int td = i % TD;
    float p = ldin(pos, posoff + td, f32);
    if (init) xf[i] = ldin(xin, i, f32) + p;
    else      xf[i] += p;
}

// ---------------------------------------------------------------------------
// LayerNorm (torch: unbiased std (n-1), eps added to std)
// ---------------------------------------------------------------------------
__global__ __launch_bounds__(256) void ln_kernel(
    const float* __restrict__ xf, const void* __restrict__ ga, size_t gaoff,
    const void* __restrict__ gb, size_t gboff,
    void* __restrict__ out, int final_o, const int* __restrict__ dflag)
{
    const bool f32 = (*dflag != 0);
    __shared__ float red[256];
    const int row = blockIdx.x;
    const int tid = threadIdx.x;
    const float* xr = xf + (size_t)row * DD;
    float x0 = xr[tid], x1 = xr[tid + 256];

    red[tid] = x0 + x1;
    __syncthreads();
    for (int o = 128; o > 0; o >>= 1) {
        if (tid < o) red[tid] += red[tid + o];
        __syncthreads();
    }
    float mean = red[0] * (1.0f / 512.0f);
    __syncthreads();
    float c0 = x0 - mean, c1 = x1 - mean;
    red[tid] = c0 * c0 + c1 * c1;
    __syncthreads();
    for (int o = 128; o > 0; o >>= 1) {
        if (tid < o) red[tid] += red[tid + o];
        __syncthreads();
    }
    float stdv = sqrtf(red[0] * (1.0f / 511.0f));
    float inv = 1.0f / (stdv + 1e-6f);
    float v0 = ldin(ga, gaoff + tid,       f32) * c0 * inv + ldin(gb, gboff + tid,       f32);
    float v1 = ldin(ga, gaoff + tid + 256, f32) * c1 * inv + ldin(gb, gboff + tid + 256, f32);
    if (final_o && f32) {
        float* orow = (float*)out + (size_t)row * DD;
        orow[tid] = v0; orow[tid + 256] = v1;
    } else {
        bf16* orow = (bf16*)out + (size_t)row * DD;
        orow[tid] = f2bf(v0); orow[tid + 256] = f2bf(v1);
    }
}

// ---------------------------------------------------------------------------
// bijective XCD swizzle for a 2D grid with (gx*gy)%8==0: each XCD gets a
// contiguous chunk of linear block ids -> L2-resident operand panels
// ---------------------------------------------------------------------------
__device__ __forceinline__ void xcd_remap(int& bx, int& by) {
    int gx = gridDim.x, gy = gridDim.y;
    int nb = gx * gy;
    int d  = by * gx + bx;
    if ((nb & 7) == 0) {
        int q = nb >> 3;
        d = (d & 7) * q + (d >> 3);
        bx = d % gx;
        by = d / gx;
    }
}

// ---------------------------------------------------------------------------
// MFMA GEMM: C[M,N] = A[M,K] @ W[N,K]^T (+bias). 128x128 tile, 4 waves.
// A: bf16 ws (a_ext=0) or raw input (a_ext=1, dtype per flag). W: bf16.
// mode 0: scatter bf16 (chunkB,H,T,DK); which=n>>9 picks q/k/v buffer (+chN)
// mode 1: relu -> bf16 [M][N]
// mode 2: fp32 += into xf [M][DD]
// ---------------------------------------------------------------------------
__global__ __launch_bounds__(256) void mgemm_kernel(
    const void* __restrict__ A, size_t aoff, int a_ext,
    const bf16* __restrict__ W,
    const void* __restrict__ b0, const void* __restrict__ b1p,
    const void* __restrict__ b2p, size_t boff,
    void* __restrict__ outp, int M, int N, int K, int mode, int chN,
    const int* __restrict__ dflag)
{
    const bool f32 = (*dflag != 0);
    const bool a32 = a_ext && f32;
    __shared__ unsigned short As[128][40];
    __shared__ unsigned short Bs[128][40];
    const int tid = threadIdx.x;
    int bx = blockIdx.x, by = blockIdx.y;
    xcd_remap(bx, by);
    const int n0 = bx * 128, m0 = by * 128;

    const int lane = tid & 63, wv = tid >> 6;
    const int wm = wv >> 1, wn = wv & 1;
    const int q = lane >> 4, lm = lane & 15;

    f32x4 acc[4][4] = {};

    for (int k0 = 0; k0 < K; k0 += 32) {
        #pragma unroll
        for (int part = 0; part < 2; ++part) {
            int idx = part * 256 + tid;
            int row = idx >> 2;
            int seg = (idx & 3) * 8;
            int grow = m0 + row; if (grow >= M) grow = M - 1;
            if (a32) {
                const float* ap = (const float*)A + aoff + (size_t)grow * K + k0 + seg;
                union { unsigned short us[8]; int4 v; } t;
                #pragma unroll
                for (int e = 0; e < 8; ++e) t.us[e] = f2us(ap[e]);
                *(int4*)&As[row][seg] = t.v;
            } else {
                *(int4*)&As[row][seg] =
                    *(const int4*)((const bf16*)A + aoff + (size_t)grow * K + k0 + seg);
            }
            *(int4*)&Bs[row][seg] =
                *(const int4*)(W + (size_t)(n0 + row) * K + k0 + seg);
        }
        __syncthreads();
        short8 af[4], bfv[4];
        #pragma unroll
        for (int i = 0; i < 4; ++i) af[i]  = *(const short8*)&As[wm * 64 + i * 16 + lm][q * 8];
        #pragma unroll
        for (int j = 0; j < 4; ++j) bfv[j] = *(const short8*)&Bs[wn * 64 + j * 16 + lm][q * 8];
        #pragma unroll
        for (int i = 0; i < 4; ++i)
            #pragma unroll
            for (int j = 0; j < 4; ++j)
                acc[i][j] = __builtin_amdgcn_mfma_f32_16x16x32_bf16(af[i], bfv[j], acc[i][j], 0, 0, 0);
        __syncthreads();
    }

    #pragma unroll
    for (int i = 0; i < 4; ++i) {
        #pragma unroll
        for (int j = 0; j < 4; ++j) {
            #pragma unroll
            for (int r = 0; r < 4; ++r) {
                int m = m0 + wm * 64 + i * 16 + q * 4 + r;
                if (m >= M) continue;
                int n = n0 + wn * 64 + j * 16 + lm;
                float c = acc[i][j][r];
                if (mode == 0) {
                    int which = n >> 9;
                    int nn = n & 511;
                    const void* bp = which == 0 ? b0 : (which == 1 ? b1p : b2p);
                    if (bp) c += ldin(bp, boff + nn, f32);
                    int b = m / TT, t = m - b * TT;
                    int h = nn >> 6, dk = nn & 63;
                    ((bf16*)outp)[(size_t)which * chN +
                                  ((((size_t)b * HH + h) * TT + t) * DK) + dk] = f2bf(c);
                } else if (mode == 1) {
                    if (b0) c += ldin(b0, boff + n, f32);
                    ((bf16*)outp)[(size_t)m * N + n] = f2bf(fmaxf(c, 0.0f));
                } else {
                    if (b0) c += ldin(b0, boff + n, f32);
                    ((float*)outp)[(size_t)m * DD + n] += c;
                }
            }
        }
    }
}

// ---------------------------------------------------------------------------
// MFMA conv1d k=3 pad=1: y[m,n] = sum_j sum_f w2r[j][n][f] * h[m+j-1,f]
// += into xf (fp32) with bias. Hb chunk-local (batch-aligned).
// ---------------------------------------------------------------------------
__global__ __launch_bounds__(256) void mconv_kernel(
    const bf16* __restrict__ Hb, const bf16* __restrict__ Wc,
    const void* __restrict__ bias, size_t boff,
    float* __restrict__ xf, int M, const int* __restrict__ dflag)
{
    const bool f32 = (*dflag != 0);
    __shared__ unsigned short As[128][40];
    __shared__ unsigned short Bs[128][40];
    const int tid = threadIdx.x;
    int bx = blockIdx.x, by = blockIdx.y;
    xcd_remap(bx, by);
    const int n0 = bx * 128, m0 = by * 128;

    const int lane = tid & 63, wv = tid >> 6;
    const int wm = wv >> 1, wn = wv & 1;
    const int q = lane >> 4, lm = lane & 15;

    // per-part staging geometry (constant across k)
    int rowP[2], segP[2], mloadP[2], trowP[2];
    bool inrP[2];
    #pragma unroll
    for (int part = 0; part < 2; ++part) {
        int idx = part * 256 + tid;
        rowP[part] = idx >> 2;
        segP[part] = (idx & 3) * 8;
        int mrow = m0 + rowP[part];
        inrP[part] = mrow < M;
        int mload = inrP[part] ? mrow : (M - 1);
        mloadP[part] = mload;
        trowP[part] = mload % TT;
    }

    f32x4 acc[4][4] = {};

    for (int j = 0; j < 3; ++j) {
        for (int k0 = 0; k0 < FF; k0 += 32) {
            #pragma unroll
            for (int part = 0; part < 2; ++part) {
                int row = rowP[part], seg = segP[part];
                int ts = trowP[part] + j - 1;
                bool valid = inrP[part] && ts >= 0 && ts < TT;
                if (valid) {
                    *(int4*)&As[row][seg] =
                        *(const int4*)(Hb + (size_t)(mloadP[part] + j - 1) * FF + k0 + seg);
                } else {
                    int4 z = {0, 0, 0, 0};
                    *(int4*)&As[row][seg] = z;
                }
                *(int4*)&Bs[row][seg] =
                    *(const int4*)(Wc + (size_t)j * 524288 + (size_t)(n0 + row) * FF + k0 + seg);
            }
            __syncthreads();
            short8 af[4], bfv[4];
            #pragma unroll
            for (int i = 0; i < 4; ++i) af[i]  = *(const short8*)&As[wm * 64 + i * 16 + lm][q * 8];
            #pragma unroll
            for (int jj = 0; jj < 4; ++jj) bfv[jj] = *(const short8*)&Bs[wn * 64 + jj * 16 + lm][q * 8];
            #pragma unroll
            for (int i = 0; i < 4; ++i)
                #pragma unroll
                for (int jj = 0; jj < 4; ++jj)
                    acc[i][jj] = __builtin_amdgcn_mfma_f32_16x16x32_bf16(af[i], bfv[jj], acc[i][jj], 0, 0, 0);
            __syncthreads();
        }
    }

    #pragma unroll
    for (int i = 0; i < 4; ++i) {
        #pragma unroll
        for (int jj = 0; jj < 4; ++jj) {
            #pragma unroll
            for (int r = 0; r < 4; ++r) {
                int m = m0 + wm * 64 + i * 16 + q * 4 + r;
                if (m >= M) continue;
                int n = n0 + wn * 64 + jj * 16 + lm;
                xf[(size_t)m * DD + n] += acc[i][jj][r] + ldin(bias, boff + n, f32);
            }
        }
    }
}

// ---------------------------------------------------------------------------
// Fused relative attention — round 6: QT=16, 38.9KB LDS (4 blocks/CU).
// V consumed directly from k-major layout via per-element B-fragment gather
// (32B-sector, L2-resident) issued before softmax. No V transpose anywhere.
// ---------------------------------------------------------------------------
__global__ __launch_bounds__(256, 4) void attn_kernel(
    const bf16* __restrict__ Q, const bf16* __restrict__ Kb,
    const bf16* __restrict__ V, const bf16* __restrict__ P,
    const void* __restrict__ ubias, const void* __restrict__ vbias, size_t uvoff,
    bf16* __restrict__ ctx, const int* __restrict__ dflag)
{
    const bool f32 = (*dflag != 0);
    // ---- dispatch swizzle: tiles of one (b,h) land on one XCD ----
    const int d  = blockIdx.x + NQT * (blockIdx.y + HH * blockIdx.z);
    const int rr = d % (8 * NQT);
    const int g  = (d / (8 * NQT)) * 8 + (rr & 7);
    const int t  = rr >> 3;                 // 0..21
    const int b  = g >> 3;                  // chunk-local batch
    const int h  = g & 7;                   // head
    const int q0 = t * QT;

    const int tid  = threadIdx.x;
    const int lane = tid & 63;
    const int wv   = tid >> 6;      // wave 0..3
    const int lm   = lane & 15;
    const int q8   = lane >> 4;

    __shared__ __align__(16) float S[QT][354];               // 22656 B
    __shared__ __align__(16) unsigned short Abf[QT][356];    // 11392 B
    __shared__ __align__(16) unsigned short qu[QT][72];      //  2304 B
    __shared__ __align__(16) unsigned short qv[QT + 2][72];  //  2592 B

    const size_t base = (((size_t)b * HH + h) * TT) * DK;
    const float scale = 0.04419417382415922f;   // 1/sqrt(512)

    // ---- phase 1: Q staging (rows q0..q0+16) ----
    for (int i = tid; i < (QT + 1) * 64; i += 256) {
        int q = i >> 6, dd = i & 63;
        int qrow = q0 + q;
        float qq = (qrow < TT) ? bf2f(Q[base + (size_t)qrow * DK + dd]) : 0.0f;
        float vb = ldin(vbias, uvoff + h * DK + dd, f32);
        qv[q][dd] = f2us((qq + vb) * scale);
        if (q < QT) {
            float ub = ldin(ubias, uvoff + h * DK + dd, f32);
            qu[q][dd] = f2us((qq + ub) * scale);
        }
    }
    __syncthreads();

    // ---- preload K and P rows for all 6 iterations ----
    short8 kv0[6], kv1[6], pv0[6], pv1[6];
    #pragma unroll
    for (int it = 0; it < 6; ++it) {
        int jt = wv + it * 4;
        int kr = jt * 16 + lm; if (kr > TT - 1) kr = TT - 1;
        const short8* kp = (const short8*)(Kb + base + (size_t)kr * DK + q8 * 8);
        const short8* pp = (const short8*)(P  + base + (size_t)kr * DK + q8 * 8);
        kv0[it] = kp[0]; kv1[it] = kp[4];
        pv0[it] = pp[0]; pv1[it] = pp[4];
    }

    // ---- phase 2: content scores -> S ----
    {
        short8 afa = *(const short8*)&qu[lm][q8 * 8];
        short8 afb = *(const short8*)&qu[lm][32 + q8 * 8];
        #pragma unroll
        for (int it = 0; it < 6; ++it) {
            int jt = wv + it * 4;
            if (jt >= NQT) break;           // wave-uniform
            f32x4 a0 = {};
            a0 = __builtin_amdgcn_mfma_f32_16x16x32_bf16(afa, kv0[it], a0, 0, 0, 0);
            a0 = __builtin_amdgcn_mfma_f32_16x16x32_bf16(afb, kv1[it], a0, 0, 0, 0);
            int col = jt * 16 + lm;         // <= 351 < 354
            #pragma unroll
            for (int r = 0; r < 4; ++r)
                S[q8 * 4 + r][col] = a0[r];
        }
    }
    __syncthreads();

    // ---- phase 3: pos scores + branchless rel-shift scatter-add ----
    {
        short8 af0a = *(const short8*)&qv[lm][q8 * 8];
        short8 af0b = *(const short8*)&qv[lm][32 + q8 * 8];
        short8 af1a = {}, af1b = {};
        if (lm == 0) {                      // second tile: only row q0+16 real
            af1a = *(const short8*)&qv[QT][q8 * 8];
            af1b = *(const short8*)&qv[QT][32 + q8 * 8];
        }
        #pragma unroll
        for (int it = 0; it < 6; ++it) {
            int jt = wv + it * 4;
            if (jt >= NQT) break;           // wave-uniform
            f32x4 ac0 = {}, ac1 = {};
            ac0 = __builtin_amdgcn_mfma_f32_16x16x32_bf16(af0a, pv0[it], ac0, 0, 0, 0);
            ac0 = __builtin_amdgcn_mfma_f32_16x16x32_bf16(af0b, pv1[it], ac0, 0, 0, 0);
            ac1 = __builtin_amdgcn_mfma_f32_16x16x32_bf16(af1a, pv0[it], ac1, 0, 0, 0);
            ac1 = __builtin_amdgcn_mfma_f32_16x16x32_bf16(af1b, pv1[it], ac1, 0, 0, 0);
            int j = jt * 16 + lm;
            if (j < TT) {
                #pragma unroll
                for (int i = 0; i < 2; ++i) {
                    #pragma unroll
                    for (int r = 0; r < 4; ++r) {
                        int rl = i * 16 + q8 * 4 + r;     // local PSraw row
                        int rg = q0 + rl;                 // global row
                        float v = (i == 0) ? ac0[r] : ac1[r];
                        // cb=0 -> (rl, j+rg-350); cb=1 -> (rl-1, j+rg+1)
                        int cb  = (j + rg < TT - 1) ? 1 : 0;
                        int row = rl - cb;
                        int col = j + rg - (TT - 1) + cb * TT;
                        if (row >= 0 && row < QT) S[row][col] += v;
                    }
                }
            }
        }
    }
    __syncthreads();

    // ---- issue V B-fragment gathers early (L2 32B sectors, hide under SM) ----
    const unsigned short* vcol = (const unsigned short*)(V + base) + (wv * 16 + lm);
    short8 bvv[11];
    #pragma unroll
    for (int ks = 0; ks < 11; ++ks) {
        #pragma unroll
        for (int e = 0; e < 8; ++e) {
            int k = ks * 32 + q8 * 8 + e;
            bvv[ks][e] = (k < TT) ? (short)vcol[(size_t)k * DK] : (short)0;
        }
    }

    // ---- phase 4: register-file softmax (16 lanes/row) ----
    {
        const int row = tid >> 4, k0 = tid & 15;
        const float* Sr = S[row];
        float sv[22];
        #pragma unroll
        for (int i = 0; i < 22; ++i) {
            int k = k0 + 16 * i;
            sv[i] = (k < TT) ? Sr[k] : -1e30f;
        }
        float m = -1e30f;
        #pragma unroll
        for (int i = 0; i < 22; ++i) m = fmaxf(m, sv[i]);
        #pragma unroll
        for (int msk = 1; msk < 16; msk <<= 1) m = fmaxf(m, __shfl_xor(m, msk));
        float sum = 0.0f;
        #pragma unroll
        for (int i = 0; i < 22; ++i) {
            float e = __expf(sv[i] - m);
            sv[i] = e;
            sum += e;
        }
        #pragma unroll
        for (int msk = 1; msk < 16; msk <<= 1) sum += __shfl_xor(sum, msk);
        float rinv = 1.0f / sum;
        #pragma unroll
        for (int i = 0; i < 23; ++i) {
            int k = k0 + 16 * i;
            if (k < 356)
                Abf[row][k] = (k < TT && i < 22) ? f2us(sv[i] * rinv) : (unsigned short)0;
        }
    }
    __syncthreads();

    // ---- phase 6: PV -> ctx ----
    {
        f32x4 a0 = {};
        #pragma unroll
        for (int ks = 0; ks < 11; ++ks) {
            short8 av = *(const short8*)&Abf[lm][ks * 32 + q8 * 8];
            a0 = __builtin_amdgcn_mfma_f32_16x16x32_bf16(av, bvv[ks], a0, 0, 0, 0);
        }
        const int dd = wv * 16 + lm;
        #pragma unroll
        for (int r = 0; r < 4; ++r) {
            int qrow = q0 + q8 * 4 + r;
            if (qrow < TT)
                ctx[((size_t)b * TT + qrow) * DD + h * DK + dd] = f2bf(a0[r]);
        }
    }
}

// ---------------------------------------------------------------------------
extern "C" void kernel_launch(void* const* d_in, const int* in_sizes, int n_in,
                              void* d_out, int out_size, void* d_ws, size_t ws_size,
                              hipStream_t stream)
{
    (void)in_sizes; (void)n_in; (void)out_size;
    const void* x    = d_in[0];
    const void* mask = d_in[1];
    const void* pos  = d_in[2];
    const void* Wq   = d_in[3];
    const void* bq   = d_in[4];
    const void* Wk   = d_in[5];
    const void* bk   = d_in[6];
    const void* Wv   = d_in[7];
    const void* bv   = d_in[8];
    const void* Wp   = d_in[9];
    const void* ub   = d_in[10];
    const void* vbi  = d_in[11];
    const void* Wo   = d_in[12];
    const void* bo   = d_in[13];
    const void* l1a  = d_in[14];
    const void* l1b  = d_in[15];
    const void* l2a  = d_in[16];
    const void* l2b  = d_in[17];
    const void* W1   = d_in[18];
    const void* b1   = d_in[19];
    const void* W2   = d_in[20];
    const void* b2   = d_in[21];
    const void* fa   = d_in[22];
    const void* fb   = d_in[23];

    const size_t exf = (size_t)MT * DD;
    char* w = (char*)d_ws;
    int*   dflag = (int*)w;
    float* xf = (float*)(w + 256);
    bf16*  xn = (bf16*)(w + 256 + exf * 4);
    bf16*  sc = (bf16*)(w + 256 + exf * 6);
    bf16*  wbuf = (bf16*)d_out;   // weights (20.4MB) live in d_out until final LN

    // runtime chunk selection from ws_size
    const size_t fixed = 256 + exf * 6;
    int cha = 8;
    if      (ws_size >= fixed + (size_t)4 * 64 * TT * DD * 2) cha = 64;
    else if (ws_size >= fixed + (size_t)4 * 32 * TT * DD * 2) cha = 32;
    else if (ws_size >= fixed + (size_t)4 * 16 * TT * DD * 2) cha = 16;
    const int nca = BB / cha;
    const int ma  = cha * TT;
    const int chf = (cha * 2 > 64) ? 64 : cha * 2;
    const int ncf = BB / chf;
    const int mf  = chf * TT;
    const int chN = cha * TT * DD;

    bf16* qc = sc;                          // Q,K,V (3 slots)
    bf16* pc = sc + (size_t)3 * chN;        // P
    bf16* hb = sc;                          // FFN h (aliases)

    dim3 blk(256);
    dim3 g_ep((MT * DD + 255) / 256);
    dim3 g_ln(MT);
    dim3 g_qkv(12, (ma + 127) / 128);
    dim3 g_p(4, (ma + 127) / 128);
    dim3 g_attn(NQT, HH, cha);
    dim3 g_o(4, (MT + 127) / 128);
    dim3 g_f1(8, (mf + 127) / 128);
    dim3 g_cv(4, (mf + 127) / 128);

    detect_kernel<<<dim3(1), dim3(64), 0, stream>>>((const unsigned short*)l1a, dflag);

    // convert weights (all layers) into d_out scratch
    auto cvt = [&](const void* src, size_t S, size_t doff, int mode) {
        dim3 g((unsigned)(((size_t)3 * S + 255) / 256));
        cvt_kernel<<<g, blk, 0, stream>>>(src, S, S, wbuf, doff, 3, mode, dflag);
    };
    cvt(Wq, 262144, OFF_QKV,          0);
    cvt(Wk, 262144, OFF_QKV + 262144, 0);
    cvt(Wv, 262144, OFF_QKV + 524288, 0);
    cvt(Wp, 262144, OFF_P,            0);
    cvt(Wo, 262144, OFF_O,            0);
    cvt(W1, 524288, OFF_W1,           0);
    cvt(W2, 1572864, OFF_W2,          1);

    for (int l = 0; l < LL; ++l) {
        const bf16* wl = wbuf + (size_t)l * LW;
        addpos_kernel<<<g_ep, blk, 0, stream>>>(x, pos, (size_t)l * TD, xf, l == 0, dflag);
        ln_kernel<<<g_ln, blk, 0, stream>>>(xf, l1a, (size_t)l * DD, l1b, (size_t)l * DD, xn, 0, dflag);
        for (int c = 0; c < nca; ++c) {
            bf16* xnc = xn + (size_t)c * ma * DD;
            mgemm_kernel<<<g_qkv, blk, 0, stream>>>(xnc, 0, 0, wl + OFF_QKV,
                bq, bk, bv, (size_t)l * DD, qc, ma, 1536, DD, 0, chN, dflag);
            mgemm_kernel<<<g_p, blk, 0, stream>>>(mask, (size_t)c * ma * DD, 1, wl + OFF_P,
                nullptr, nullptr, nullptr, 0, pc, ma, DD, DD, 0, 0, dflag);
            attn_kernel<<<g_attn, blk, 0, stream>>>(qc, qc + chN, qc + 2 * (size_t)chN, pc,
                ub, vbi, (size_t)l * HH * DK, xnc, dflag);
        }
        mgemm_kernel<<<g_o, blk, 0, stream>>>(xn, 0, 0, wl + OFF_O,
            bo, nullptr, nullptr, (size_t)l * DD, xf, MT, DD, DD, 2, 0, dflag);
        ln_kernel<<<g_ln, blk, 0, stream>>>(xf, l2a, (size_t)l * DD, l2b, (size_t)l * DD, xn, 0, dflag);
        for (int c = 0; c < ncf; ++c) {
            mgemm_kernel<<<g_f1, blk, 0, stream>>>(xn + (size_t)c * mf * DD, 0, 0, wl + OFF_W1,
                b1, nullptr, nullptr, (size_t)l * FF, hb, mf, FF, DD, 1, 0, dflag);
            mconv_kernel<<<g_cv, blk, 0, stream>>>(hb, wl + OFF_W2,
                b2, (size_t)l * DD, xf + (size_t)c * mf * DD, mf, dflag);
        }
    }
    ln_kernel<<<g_ln, blk, 0, stream>>>(xf, fa, 0, fb, 0, d_out, 1, dflag);
}